// Round 1
// baseline (229.478 us; speedup 1.0000x reference)
//
#include <hip/hip_runtime.h>

// Problem constants (MyAttention_24790551232728)
#define BW   2
#define TT   4096
#define DD   768
#define HH   4
#define DHH  64
#define DOO  256
#define W1C  7
#define W2C  15
#define TPC  (TT + 2*W1C)     // 4110 padded sequence length
#define MROWS (BW*TPC)        // 8220 projection rows
#define MTOT  (MROWS + W2C)   // 8235 (+15 pos_emb rows ride along in the GEMM)
#define NN   512              // 256 q-cols ++ 256 v-cols

// GEMM: C[MTOT][512] = A @ [Wq;Wv]^T (+bias for the first MROWS rows).
// A rows: zero-padded inputs [B, T+14, D]; last 15 rows are pos_emb.
// Tile 64x64, BK=16, 256 threads, 4x4 micro-tile per thread.
// Both LDS tiles stored k-major [16][64]: A-fragment reads are wave-broadcast,
// B-fragment reads are contiguous float4 (ds_read_b128).
__global__ __launch_bounds__(256) void proj_gemm(
    const float* __restrict__ inp,   // [B,T,D]
    const float* __restrict__ Wq,    // [256,768] row-major
    const float* __restrict__ bq,    // [256]
    const float* __restrict__ Wv,    // [256,768]
    const float* __restrict__ bv,    // [256]
    const float* __restrict__ pos,   // [15,768]
    float* __restrict__ q_pad,       // [B,TP,256]
    float* __restrict__ v_pad,       // [B,TP,256]
    float* __restrict__ pos_q,       // [15,256]
    float* __restrict__ pos_v)       // [15,256]
{
  __shared__ float As[16][64];
  __shared__ float Bs[16][64];
  const int tid = threadIdx.x;
  const int tx = tid & 15, ty = tid >> 4;
  const int m0 = blockIdx.x * 64;
  const int n0 = blockIdx.y * 64;

  float acc[4][4];
  #pragma unroll
  for (int i = 0; i < 4; i++)
    #pragma unroll
    for (int j = 0; j < 4; j++) acc[i][j] = 0.f;

  // staging-load index split: 256 threads x float4 = 1024 elems = 64x16 tile
  const int arow = tid >> 2;        // 0..63  (m within tile)
  const int akc  = (tid & 3) * 4;   // 0,4,8,12 (k within tile)
  const int brow = tid & 63;        // 0..63  (n within tile)
  const int bkc  = (tid >> 6) * 4;  // 0,4,8,12

  // resolve A source row once (zero pad rows -> nullptr -> zeros)
  const int am = m0 + arow;
  const float* arow_ptr = nullptr;
  if (am < MROWS) {
    int b = am / TPC, tp = am - b * TPC, t = tp - W1C;
    if (t >= 0 && t < TT) arow_ptr = inp + ((size_t)b * TT + t) * DD;
  } else if (am < MTOT) {
    arow_ptr = pos + (size_t)(am - MROWS) * DD;
  }
  const int bn = n0 + brow;
  const float* wrow_ptr = (bn < DOO) ? (Wq + (size_t)bn * DD)
                                     : (Wv + (size_t)(bn - DOO) * DD);

  for (int k0 = 0; k0 < DD; k0 += 16) {
    float4 av = make_float4(0.f, 0.f, 0.f, 0.f);
    if (arow_ptr) av = *(const float4*)(arow_ptr + k0 + akc);
    As[akc + 0][arow] = av.x;
    As[akc + 1][arow] = av.y;
    As[akc + 2][arow] = av.z;
    As[akc + 3][arow] = av.w;
    float4 wv4 = *(const float4*)(wrow_ptr + k0 + bkc);
    Bs[bkc + 0][brow] = wv4.x;
    Bs[bkc + 1][brow] = wv4.y;
    Bs[bkc + 2][brow] = wv4.z;
    Bs[bkc + 3][brow] = wv4.w;
    __syncthreads();
    #pragma unroll
    for (int k = 0; k < 16; k++) {
      float4 a  = *(const float4*)&As[k][ty * 4];   // broadcast within ty-group
      float4 bb = *(const float4*)&Bs[k][tx * 4];   // contiguous b128
      float aa[4] = {a.x, a.y, a.z, a.w};
      float bv4[4] = {bb.x, bb.y, bb.z, bb.w};
      #pragma unroll
      for (int i = 0; i < 4; i++)
        #pragma unroll
        for (int j = 0; j < 4; j++)
          acc[i][j] += aa[i] * bv4[j];
    }
    __syncthreads();
  }

  // epilogue: bias + scatter to q_pad/v_pad/pos_q/pos_v
  #pragma unroll
  for (int i = 0; i < 4; i++) {
    int m = m0 + ty * 4 + i;
    if (m >= MTOT) continue;
    #pragma unroll
    for (int j = 0; j < 4; j++) {
      int n = n0 + tx * 4 + j;
      float v = acc[i][j];
      if (m < MROWS) {
        v += (n < DOO) ? bq[n] : bv[n - DOO];
        int b = m / TPC, tp = m - b * TPC;
        if (n < DOO) q_pad[((size_t)b * TPC + tp) * DOO + n] = v;
        else         v_pad[((size_t)b * TPC + tp) * DOO + (n - DOO)] = v;
      } else {
        int w = m - MROWS;
        if (n < DOO) pos_q[w * DOO + n] = v;
        else         pos_v[w * DOO + (n - DOO)] = v;
      }
    }
  }
}

// Window attention: one wave per (b,t,h); lane = d within the head.
// s_w = q . (q_pad[t+w] + pos_q[w])  via 6-step butterfly reduction,
// acc += s_w * (v_pad[t+w] + pos_v[w]).  No softmax, no scaling (per ref).
__global__ __launch_bounds__(256) void win_attn(
    const float* __restrict__ q_pad,
    const float* __restrict__ v_pad,
    const float* __restrict__ pos_q,
    const float* __restrict__ pos_v,
    float* __restrict__ out)         // [B,T,256]
{
  const int wid  = blockIdx.x * 4 + (threadIdx.x >> 6);
  const int lane = threadIdx.x & 63;
  const int h = wid & (HH - 1);
  const int t = (wid >> 2) & (TT - 1);
  const int b = wid >> 14;                 // / (H*T) = / 16384
  const int c = h * DHH + lane;            // column in DO

  const float q = q_pad[((size_t)b * TPC + t + W1C) * DOO + c];
  const float* kbase = q_pad + ((size_t)b * TPC + t) * DOO + c;
  const float* vbase = v_pad + ((size_t)b * TPC + t) * DOO + c;

  // preload position projections for this column (resident across the loop)
  float pq[W2C], pv[W2C];
  #pragma unroll
  for (int w = 0; w < W2C; w++) {
    pq[w] = pos_q[w * DOO + c];
    pv[w] = pos_v[w * DOO + c];
  }

  float acc = 0.f;
  #pragma unroll
  for (int w = 0; w < W2C; w++) {
    float kk = kbase[(size_t)w * DOO] + pq[w];
    float p = q * kk;
    #pragma unroll
    for (int off = 1; off < 64; off <<= 1)
      p += __shfl_xor(p, off, 64);         // all lanes end with s_w
    float vv = vbase[(size_t)w * DOO] + pv[w];
    acc += p * vv;
  }
  out[((size_t)b * TT + t) * DOO + c] = acc;
}

extern "C" void kernel_launch(void* const* d_in, const int* in_sizes, int n_in,
                              void* d_out, int out_size, void* d_ws, size_t ws_size,
                              hipStream_t stream) {
  const float* inp = (const float*)d_in[0];
  const float* Wq  = (const float*)d_in[1];
  const float* bq  = (const float*)d_in[2];
  const float* Wv  = (const float*)d_in[3];
  const float* bv  = (const float*)d_in[4];
  const float* pos = (const float*)d_in[5];
  float* out = (float*)d_out;

  float* q_pad = (float*)d_ws;                                  // [B,TP,256]
  float* v_pad = q_pad + (size_t)BW * TPC * DOO;                // [B,TP,256]
  float* pos_q = v_pad + (size_t)BW * TPC * DOO;                // [15,256]
  float* pos_v = pos_q + (size_t)W2C * DOO;                     // [15,256]
  // total ws use: ~16.9 MB

  dim3 g1((MTOT + 63) / 64, NN / 64);                            // 129 x 8
  hipLaunchKernelGGL(proj_gemm, g1, dim3(256), 0, stream,
                     inp, Wq, bq, Wv, bv, pos, q_pad, v_pad, pos_q, pos_v);

  const int nblocks = (BW * TT * HH) / 4;                        // 8192
  hipLaunchKernelGGL(win_attn, dim3(nblocks), dim3(256), 0, stream,
                     q_pad, v_pad, pos_q, pos_v, out);
}

// Round 2
// 119.522 us; speedup vs baseline: 1.9200x; 1.9200x over previous
//
#include <hip/hip_runtime.h>

// MyAttention: B=2, T=4096, D=768, DO=256, H=4, DH=64, W2=15
#define TPC   4110            // T + 14 (padded seq)
#define MROWS 8220            // B * TPC
#define MTOT  8235            // + 15 pos rows
#define MPAD  8320            // padded to 65 * 128
#define KD    768
#define NSTR  4               // 4 n-strips of 128 (q:0-1, v:2-3)

typedef __attribute__((ext_vector_type(8))) short short8;
typedef __attribute__((ext_vector_type(4))) float f32x4;

#define LOAD_LDS16(gp, lp)                                                   \
  __builtin_amdgcn_global_load_lds(                                          \
      (const __attribute__((address_space(1))) void*)(gp),                   \
      (__attribute__((address_space(3))) void*)(lp), 16, 0, 0)

__device__ inline unsigned bfr(float x) {
  unsigned u = __float_as_uint(x);
  return (u + 0x7FFFu + ((u >> 16) & 1u)) >> 16;   // RNE fp32->bf16
}
__device__ inline unsigned pack2(float a, float b) {
  return bfr(a) | (bfr(b) << 16);
}

// ---------------------------------------------------------------------------
// Pass 1: cast A (zero-padded inputs + pos rows) and W ([Wq;Wv]) to bf16.
// Each thread writes one 16B chunk (8 bf16).
__global__ __launch_bounds__(256) void cast_pass(
    const float* __restrict__ inp, const float* __restrict__ Wq,
    const float* __restrict__ Wv, const float* __restrict__ pos,
    ushort* __restrict__ Abf, ushort* __restrict__ Wbf) {
  const int ACH = MPAD * 96;            // 96 chunks of 8 per 768-row
  int gid = blockIdx.x * 256 + threadIdx.x;
  const float* src = nullptr;
  ushort* dst;
  if (gid < ACH) {
    int row = gid / 96, c = (gid - row * 96) * 8;
    dst = Abf + (size_t)row * KD + c;
    if (row < MROWS) {
      int b = row / TPC, tp = row - b * TPC, t = tp - 7;
      if (t >= 0 && t < 4096) src = inp + ((size_t)b * 4096 + t) * KD + c;
    } else if (row < MTOT) {
      src = pos + (size_t)(row - MROWS) * KD + c;
    }
  } else {
    int wid = gid - ACH;
    if (wid >= 512 * 96) return;
    int row = wid / 96, c = (wid - row * 96) * 8;
    dst = Wbf + (size_t)row * KD + c;
    src = (row < 256) ? Wq + (size_t)row * KD + c
                      : Wv + (size_t)(row - 256) * KD + c;
  }
  uint4 o;
  if (src) {
    float4 f0 = *(const float4*)src;
    float4 f1 = *(const float4*)(src + 4);
    o.x = pack2(f0.x, f0.y); o.y = pack2(f0.z, f0.w);
    o.z = pack2(f1.x, f1.y); o.w = pack2(f1.z, f1.w);
  } else {
    o.x = o.y = o.z = o.w = 0u;
  }
  *(uint4*)dst = o;
}

// ---------------------------------------------------------------------------
// Pass 2: C[8320][512] = Abf @ Wbf^T, bf16 MFMA 16x16x32, 128x128 tiles,
// BK=32, global_load_lds width-16 staging (m97 pattern). fp32 epilogue + bias.
__global__ __launch_bounds__(256) void proj_gemm_bf16(
    const ushort* __restrict__ Abf, const ushort* __restrict__ Wbf,
    const float* __restrict__ bq, const float* __restrict__ bv,
    float* __restrict__ q_out, float* __restrict__ v_out) {
  __shared__ ushort Alds[128 * 32];
  __shared__ ushort Blds[128 * 32];
  const int tid = threadIdx.x;
  const int wave = tid >> 6, lane = tid & 63;
  const int nstrip = blockIdx.x;        // 0..3
  const int m0 = blockIdx.y * 128;
  const int wm = wave & 1, wn = wave >> 1;
  const int fr = lane & 15, quad = lane >> 4;

  f32x4 acc[4][4];
  #pragma unroll
  for (int i = 0; i < 4; i++)
    #pragma unroll
    for (int j = 0; j < 4; j++) acc[i][j] = 0.0f;

  // staging: chunk c=(issue*256+tid) -> row=c>>2 (tile row), g=c&3 (16B k-grp)
  const int r0 = tid >> 2, g0 = (tid & 3) * 8;     // issue 0
  const size_t a_base0 = (size_t)(m0 + r0) * KD + g0;
  const size_t a_base1 = (size_t)(m0 + 64 + r0) * KD + g0;
  const size_t b_base0 = (size_t)(nstrip * 128 + r0) * KD + g0;
  const size_t b_base1 = (size_t)(nstrip * 128 + 64 + r0) * KD + g0;
  ushort* aw0 = Alds + (size_t)(wave * 64) * 8;
  ushort* aw1 = Alds + (size_t)(256 + wave * 64) * 8;
  ushort* bw0 = Blds + (size_t)(wave * 64) * 8;
  ushort* bw1 = Blds + (size_t)(256 + wave * 64) * 8;

  for (int k0 = 0; k0 < KD; k0 += 32) {
    LOAD_LDS16(Abf + a_base0 + k0, aw0);
    LOAD_LDS16(Abf + a_base1 + k0, aw1);
    LOAD_LDS16(Wbf + b_base0 + k0, bw0);
    LOAD_LDS16(Wbf + b_base1 + k0, bw1);
    __syncthreads();
    short8 a[4], b[4];
    #pragma unroll
    for (int i = 0; i < 4; i++)
      a[i] = *(const short8*)(Alds + (wm * 64 + i * 16 + fr) * 32 + quad * 8);
    #pragma unroll
    for (int j = 0; j < 4; j++)
      b[j] = *(const short8*)(Blds + (wn * 64 + j * 16 + fr) * 32 + quad * 8);
    #pragma unroll
    for (int i = 0; i < 4; i++)
      #pragma unroll
      for (int j = 0; j < 4; j++)
        acc[i][j] = __builtin_amdgcn_mfma_f32_16x16x32_bf16(a[i], b[j],
                                                            acc[i][j], 0, 0, 0);
    __syncthreads();
  }

  // epilogue: C/D layout col=lane&15, row=quad*4+reg
  const float* bias = (nstrip < 2) ? bq : bv;
  float* dst = (nstrip < 2) ? q_out : v_out;
  const int colb = (nstrip & 1) * 128;
  #pragma unroll
  for (int j = 0; j < 4; j++) {
    int col = colb + wn * 64 + j * 16 + fr;
    float bj = bias[col];
    #pragma unroll
    for (int i = 0; i < 4; i++) {
      int mbase = m0 + wm * 64 + i * 16 + quad * 4;
      #pragma unroll
      for (int r = 0; r < 4; r++) {
        int m = mbase + r;
        if (m < MTOT) {
          float v = acc[i][j][r] + (m < MROWS ? bj : 0.0f);
          dst[(size_t)m * 256 + col] = v;
        }
      }
    }
  }
}

// ---------------------------------------------------------------------------
// Pass 3: windowed attention, fp32, LDS-tiled.
// Block = (b, h, 64-t tile). Thread = (t_local, quarter of DH=16 dims).
// s[w] = q . (k[t+w]+pq[w]) via 2-step 4-lane shuffle; ctx += s*(v+pv).
__global__ __launch_bounds__(256) void win_attn2(
    const float* __restrict__ q_out, const float* __restrict__ v_out,
    float* __restrict__ out) {
  __shared__ __align__(16) float ks[78][68];
  __shared__ __align__(16) float vs[78][68];
  __shared__ __align__(16) float pq[15][68];
  __shared__ __align__(16) float pv[15][68];
  const int tid = threadIdx.x;
  const int bh = blockIdx.x >> 6, tile = blockIdx.x & 63;
  const int b = bh >> 2, h = bh & 3;
  const int t0 = tile * 64;
  const int colbase = h * 64;

  for (int idx = tid; idx < 78 * 16; idx += 256) {
    int row = idx >> 4, c4 = (idx & 15) * 4;
    size_t go = ((size_t)(b * TPC + t0 + row)) * 256 + colbase + c4;
    *(float4*)&ks[row][c4] = *(const float4*)(q_out + go);
    *(float4*)&vs[row][c4] = *(const float4*)(v_out + go);
  }
  if (tid < 15 * 16) {
    int row = tid >> 4, c4 = (tid & 15) * 4;
    size_t go = ((size_t)(MROWS + row)) * 256 + colbase + c4;
    *(float4*)&pq[row][c4] = *(const float4*)(q_out + go);
    *(float4*)&pv[row][c4] = *(const float4*)(v_out + go);
  }
  __syncthreads();

  const int tl = tid >> 2, qtr = tid & 3, d0 = qtr * 16;
  float4 qv[4];
  #pragma unroll
  for (int c = 0; c < 4; c++) qv[c] = *(float4*)&ks[tl + 7][d0 + c * 4];
  float4 ctx[4];
  #pragma unroll
  for (int c = 0; c < 4; c++) ctx[c] = make_float4(0.f, 0.f, 0.f, 0.f);

  #pragma unroll
  for (int w = 0; w < 15; w++) {
    float p = 0.f;
    #pragma unroll
    for (int c = 0; c < 4; c++) {
      float4 kk = *(float4*)&ks[tl + w][d0 + c * 4];
      float4 pp = *(float4*)&pq[w][d0 + c * 4];
      p += qv[c].x * (kk.x + pp.x) + qv[c].y * (kk.y + pp.y) +
           qv[c].z * (kk.z + pp.z) + qv[c].w * (kk.w + pp.w);
    }
    p += __shfl_xor(p, 1, 64);
    p += __shfl_xor(p, 2, 64);
    #pragma unroll
    for (int c = 0; c < 4; c++) {
      float4 vv = *(float4*)&vs[tl + w][d0 + c * 4];
      float4 pp = *(float4*)&pv[w][d0 + c * 4];
      ctx[c].x += p * (vv.x + pp.x);
      ctx[c].y += p * (vv.y + pp.y);
      ctx[c].z += p * (vv.z + pp.z);
      ctx[c].w += p * (vv.w + pp.w);
    }
  }
  size_t oo = ((size_t)(b * 4096 + t0 + tl)) * 256 + colbase + d0;
  #pragma unroll
  for (int c = 0; c < 4; c++) *(float4*)(out + oo + c * 4) = ctx[c];
}

// ---------------------------------------------------------------------------
extern "C" void kernel_launch(void* const* d_in, const int* in_sizes, int n_in,
                              void* d_out, int out_size, void* d_ws,
                              size_t ws_size, hipStream_t stream) {
  const float* inp = (const float*)d_in[0];
  const float* Wq  = (const float*)d_in[1];
  const float* bq  = (const float*)d_in[2];
  const float* Wv  = (const float*)d_in[3];
  const float* bv  = (const float*)d_in[4];
  const float* pos = (const float*)d_in[5];
  float* out = (float*)d_out;

  // ws layout (bytes): Abf 12,779,520 | Wbf 786,432 | q_out 8,519,680 |
  // v_out 8,519,680  -> total ~30.6 MB
  char* ws = (char*)d_ws;
  ushort* Abf  = (ushort*)ws;
  ushort* Wbf  = (ushort*)(ws + 12779520);
  float*  q_out = (float*)(ws + 13565952);   // [8320][256]; rows 8220..8234 = pos_q
  float*  v_out = (float*)(ws + 22085632);

  const int cast_chunks = MPAD * 96 + 512 * 96;        // 847,872
  hipLaunchKernelGGL(cast_pass, dim3(cast_chunks / 256), dim3(256), 0, stream,
                     inp, Wq, Wv, pos, Abf, Wbf);
  hipLaunchKernelGGL(proj_gemm_bf16, dim3(NSTR, MPAD / 128), dim3(256), 0,
                     stream, Abf, Wbf, bq, bv, q_out, v_out);
  hipLaunchKernelGGL(win_attn2, dim3(2 * 4 * 64), dim3(256), 0, stream,
                     q_out, v_out, out);
}

// Round 3
// 116.016 us; speedup vs baseline: 1.9780x; 1.0302x over previous
//
#include <hip/hip_runtime.h>

// MyAttention: B=2, T=4096, D=768, DO=256, H=4, DH=64, W2=15
#define TPC   4110            // T + 14 (padded seq)
#define MROWS 8220            // B * TPC
#define MTOT  8235            // + 15 pos rows
#define KD    768

typedef __attribute__((ext_vector_type(8))) short short8;
typedef __attribute__((ext_vector_type(4))) float f32x4;

__device__ inline unsigned bfr(float x) {
  unsigned u = __float_as_uint(x);
  return (u + 0x7FFFu + ((u >> 16) & 1u)) >> 16;   // RNE fp32->bf16
}
__device__ inline unsigned pack2(float a, float b) {
  return bfr(a) | (bfr(b) << 16);
}

// ---------------------------------------------------------------------------
// Fused cast+GEMM: C[8320][512] = A @ [Wq;Wv]^T (bf16 MFMA, fp32 epilogue).
// A rows = zero-padded inputs (+15 pos rows), cast to bf16 in-register during
// LDS staging. Tile 64(m) x 128(n), BK=32, 256 threads (2x2 waves of 32x64).
// blockIdx.x = n-strip (0..3; strips 0-1 -> q, 2-3 -> v) so the 4 blocks
// sharing an A-tile are dispatch-adjacent. Register-prefetch pipeline.
// Output layout: q_out/v_out [B][H][TPC][64] (attention-friendly); pos rows
// go to separate pos_q/pos_v [15][256].
__global__ __launch_bounds__(256, 3) void proj_fused(
    const float* __restrict__ inp, const float* __restrict__ Wq,
    const float* __restrict__ bq, const float* __restrict__ Wv,
    const float* __restrict__ bv, const float* __restrict__ pos,
    float* __restrict__ q_out, float* __restrict__ v_out,
    float* __restrict__ pos_q, float* __restrict__ pos_v) {
  __shared__ ushort Al[64 * 32];
  __shared__ ushort Bl[128 * 32];
  const int tid = threadIdx.x;
  const int wave = tid >> 6, lane = tid & 63;
  const int ns = blockIdx.x;            // 0..3
  const int m0 = blockIdx.y * 64;
  const int wm = wave & 1, wn = wave >> 1;
  const int fr = lane & 15, quad = lane >> 4;

  // staging assignment: thread -> (row sr, 8-elem k-chunk kc)
  const int sr = tid >> 2;              // 0..63
  const int kc = (tid & 3) * 8;         // 0,8,16,24

  // A source row (nullptr => zero pad row)
  const int am = m0 + sr;
  const float* aptr = nullptr;
  if (am < MROWS) {
    int b = am / TPC, t = am - b * TPC - 7;
    if (t >= 0 && t < 4096) aptr = inp + ((size_t)b * 4096 + t) * KD + kc;
  } else if (am < MTOT) {
    aptr = pos + (size_t)(am - MROWS) * KD + kc;
  }
  const float* wsrc = (ns < 2) ? Wq : Wv;
  const int wbase = (ns & 1) * 128;
  const float* bptr0 = wsrc + (size_t)(wbase + sr) * KD + kc;       // rows 0..63
  const float* bptr1 = wsrc + (size_t)(wbase + 64 + sr) * KD + kc;  // rows 64..127

  ushort* adst  = Al + sr * 32 + kc;
  ushort* bdst0 = Bl + sr * 32 + kc;
  ushort* bdst1 = Bl + (64 + sr) * 32 + kc;

  f32x4 acc[2][4];
  #pragma unroll
  for (int i = 0; i < 2; i++)
    #pragma unroll
    for (int j = 0; j < 4; j++) acc[i][j] = 0.0f;

  float4 ra0, ra1, rb00, rb01, rb10, rb11;
  // prefetch k-tile 0
  if (aptr) { ra0 = *(const float4*)(aptr); ra1 = *(const float4*)(aptr + 4); }
  else      { ra0 = ra1 = make_float4(0.f, 0.f, 0.f, 0.f); }
  rb00 = *(const float4*)(bptr0); rb01 = *(const float4*)(bptr0 + 4);
  rb10 = *(const float4*)(bptr1); rb11 = *(const float4*)(bptr1 + 4);

  for (int k0 = 0; k0 < KD; k0 += 32) {
    // convert + stage current k-tile
    uint4 o;
    o.x = pack2(ra0.x, ra0.y); o.y = pack2(ra0.z, ra0.w);
    o.z = pack2(ra1.x, ra1.y); o.w = pack2(ra1.z, ra1.w);
    *(uint4*)adst = o;
    o.x = pack2(rb00.x, rb00.y); o.y = pack2(rb00.z, rb00.w);
    o.z = pack2(rb01.x, rb01.y); o.w = pack2(rb01.z, rb01.w);
    *(uint4*)bdst0 = o;
    o.x = pack2(rb10.x, rb10.y); o.y = pack2(rb10.z, rb10.w);
    o.z = pack2(rb11.x, rb11.y); o.w = pack2(rb11.z, rb11.w);
    *(uint4*)bdst1 = o;

    // issue next k-tile's global loads (overlap with MFMA below)
    float4 na0, na1, nb00, nb01, nb10, nb11;
    const bool more = (k0 + 32 < KD);
    if (more) {
      int kn = k0 + 32;
      if (aptr) { na0 = *(const float4*)(aptr + kn); na1 = *(const float4*)(aptr + kn + 4); }
      else      { na0 = na1 = make_float4(0.f, 0.f, 0.f, 0.f); }
      nb00 = *(const float4*)(bptr0 + kn); nb01 = *(const float4*)(bptr0 + kn + 4);
      nb10 = *(const float4*)(bptr1 + kn); nb11 = *(const float4*)(bptr1 + kn + 4);
    }
    __syncthreads();
    short8 af[2], bf[4];
    #pragma unroll
    for (int i = 0; i < 2; i++)
      af[i] = *(const short8*)(Al + (wm * 32 + i * 16 + fr) * 32 + quad * 8);
    #pragma unroll
    for (int j = 0; j < 4; j++)
      bf[j] = *(const short8*)(Bl + (wn * 64 + j * 16 + fr) * 32 + quad * 8);
    #pragma unroll
    for (int i = 0; i < 2; i++)
      #pragma unroll
      for (int j = 0; j < 4; j++)
        acc[i][j] = __builtin_amdgcn_mfma_f32_16x16x32_bf16(af[i], bf[j],
                                                            acc[i][j], 0, 0, 0);
    __syncthreads();
    if (more) {
      ra0 = na0; ra1 = na1;
      rb00 = nb00; rb01 = nb01; rb10 = nb10; rb11 = nb11;
    }
  }

  // epilogue: C/D layout col=lane&15, row=quad*4+reg
  const float* bias = (ns < 2) ? bq : bv;
  float* outp = (ns < 2) ? q_out : v_out;
  float* posp = (ns < 2) ? pos_q : pos_v;
  #pragma unroll
  for (int j = 0; j < 4; j++) {
    const int colq = wbase + wn * 64 + j * 16 + fr;   // 0..255
    const int h = colq >> 6, d = colq & 63;
    const float bj = bias[colq];
    #pragma unroll
    for (int i = 0; i < 2; i++) {
      const int mb = m0 + wm * 32 + i * 16 + quad * 4;
      #pragma unroll
      for (int r = 0; r < 4; r++) {
        const int m = mb + r;
        if (m < MROWS) {
          int b = m / TPC, tp = m - b * TPC;
          outp[(((size_t)(b * 4 + h)) * TPC + tp) * 64 + d] = acc[i][j][r] + bj;
        } else if (m < MTOT) {
          posp[(m - MROWS) * 256 + colq] = acc[i][j][r];
        }
      }
    }
  }
}

// ---------------------------------------------------------------------------
// Windowed attention, fp32, LDS-tiled. Block = (b, h, 64-t tile); the
// [B][H][TPC][64] layout makes the 78-row k/v slab one contiguous segment.
// Thread = (t_local, quarter of DH); 2-step 4-lane shuffle for the dot.
__global__ __launch_bounds__(256) void win_attn3(
    const float* __restrict__ q_out, const float* __restrict__ v_out,
    const float* __restrict__ pos_q, const float* __restrict__ pos_v,
    float* __restrict__ out) {
  __shared__ __align__(16) float ks[78][68];
  __shared__ __align__(16) float vs[78][68];
  __shared__ __align__(16) float pq[15][68];
  __shared__ __align__(16) float pv[15][68];
  const int tid = threadIdx.x;
  const int bh = blockIdx.x >> 6, tile = blockIdx.x & 63;
  const int b = bh >> 2, h = bh & 3;
  const int t0 = tile * 64;

  const size_t slab = (((size_t)(b * 4 + h)) * TPC + t0) * 64;
  const float4* kq4 = (const float4*)(q_out + slab);
  const float4* vv4 = (const float4*)(v_out + slab);
  for (int idx = tid; idx < 78 * 16; idx += 256) {
    int row = idx >> 4, c4 = (idx & 15) * 4;
    *(float4*)&ks[row][c4] = kq4[idx];
    *(float4*)&vs[row][c4] = vv4[idx];
  }
  if (tid < 15 * 16) {
    int row = tid >> 4, c4 = (tid & 15) * 4;
    *(float4*)&pq[row][c4] = *(const float4*)(pos_q + row * 256 + h * 64 + c4);
    *(float4*)&pv[row][c4] = *(const float4*)(pos_v + row * 256 + h * 64 + c4);
  }
  __syncthreads();

  const int tl = tid >> 2, qtr = tid & 3, d0 = qtr * 16;
  float4 qv[4];
  #pragma unroll
  for (int c = 0; c < 4; c++) qv[c] = *(float4*)&ks[tl + 7][d0 + c * 4];
  float4 ctx[4];
  #pragma unroll
  for (int c = 0; c < 4; c++) ctx[c] = make_float4(0.f, 0.f, 0.f, 0.f);

  #pragma unroll
  for (int w = 0; w < 15; w++) {
    float p = 0.f;
    #pragma unroll
    for (int c = 0; c < 4; c++) {
      float4 kk = *(float4*)&ks[tl + w][d0 + c * 4];
      float4 pp = *(float4*)&pq[w][d0 + c * 4];
      p += qv[c].x * (kk.x + pp.x) + qv[c].y * (kk.y + pp.y) +
           qv[c].z * (kk.z + pp.z) + qv[c].w * (kk.w + pp.w);
    }
    p += __shfl_xor(p, 1, 64);
    p += __shfl_xor(p, 2, 64);
    #pragma unroll
    for (int c = 0; c < 4; c++) {
      float4 vv = *(float4*)&vs[tl + w][d0 + c * 4];
      float4 pp = *(float4*)&pv[w][d0 + c * 4];
      ctx[c].x += p * (vv.x + pp.x);
      ctx[c].y += p * (vv.y + pp.y);
      ctx[c].z += p * (vv.z + pp.z);
      ctx[c].w += p * (vv.w + pp.w);
    }
  }
  size_t oo = ((size_t)(b * 4096 + t0 + tl)) * 256 + h * 64 + d0;
  #pragma unroll
  for (int c = 0; c < 4; c++) *(float4*)(out + oo + c * 4) = ctx[c];
}

// ---------------------------------------------------------------------------
extern "C" void kernel_launch(void* const* d_in, const int* in_sizes, int n_in,
                              void* d_out, int out_size, void* d_ws,
                              size_t ws_size, hipStream_t stream) {
  const float* inp = (const float*)d_in[0];
  const float* Wq  = (const float*)d_in[1];
  const float* bq  = (const float*)d_in[2];
  const float* Wv  = (const float*)d_in[3];
  const float* bv  = (const float*)d_in[4];
  const float* pos = (const float*)d_in[5];
  float* out = (float*)d_out;

  // ws layout (bytes): q_out 8,417,280 | v_out 8,417,280 | pos_q 15,360 |
  // pos_v 15,360  -> ~16.9 MB
  char* ws = (char*)d_ws;
  float* q_out = (float*)ws;                       // [B][H][TPC][64]
  float* v_out = (float*)(ws + 8417280);           // [B][H][TPC][64]
  float* pos_q = (float*)(ws + 16834560);          // [15][256]
  float* pos_v = (float*)(ws + 16849920);          // [15][256]

  hipLaunchKernelGGL(proj_fused, dim3(4, 130), dim3(256), 0, stream,
                     inp, Wq, bq, Wv, bv, pos, q_out, v_out, pos_q, pos_v);
  hipLaunchKernelGGL(win_attn3, dim3(2 * 4 * 64), dim3(256), 0, stream,
                     q_out, v_out, pos_q, pos_v, out);
}

// Round 4
// 113.141 us; speedup vs baseline: 2.0282x; 1.0254x over previous
//
#include <hip/hip_runtime.h>

// MyAttention: B=2, T=4096, D=768, DO=256, H=4, DH=64, W2=15
#define TPC   4110            // T + 14 (padded seq)
#define MROWS 8220            // B * TPC
#define MTOT  8235            // + 15 pos rows
#define MPAD  8320            // 130 * 64
#define KD    768

typedef __attribute__((ext_vector_type(8))) short short8;
typedef __attribute__((ext_vector_type(4))) float f32x4;

#define LOAD_LDS16(gp, lp)                                                   \
  __builtin_amdgcn_global_load_lds(                                          \
      (const __attribute__((address_space(1))) void*)(gp),                   \
      (__attribute__((address_space(3))) void*)(lp), 16, 0, 0)

__device__ inline unsigned bfr(float x) {
  unsigned u = __float_as_uint(x);
  return (u + 0x7FFFu + ((u >> 16) & 1u)) >> 16;   // RNE fp32->bf16
}
__device__ inline unsigned pack2(float a, float b) {
  return bfr(a) | (bfr(b) << 16);
}
__device__ inline float bflo(unsigned u) { return __uint_as_float(u << 16); }
__device__ inline float bfhi(unsigned u) { return __uint_as_float(u & 0xffff0000u); }

// ---------------------------------------------------------------------------
// Pass 1: cast A (zero-padded inputs + 15 pos rows, MPAD x 768) and W
// ([Wq;Wv], 512 x 768) to bf16. One 16B chunk (8 bf16) per thread.
__global__ __launch_bounds__(256) void cast_ab(
    const float* __restrict__ inp, const float* __restrict__ Wq,
    const float* __restrict__ Wv, const float* __restrict__ pos,
    ushort* __restrict__ Abf, ushort* __restrict__ Wbf) {
  const int ACH = MPAD * 96;
  int gid = blockIdx.x * 256 + threadIdx.x;
  const float* src = nullptr;
  ushort* dst;
  if (gid < ACH) {
    int row = gid / 96, c = (gid - row * 96) * 8;
    dst = Abf + (size_t)row * KD + c;
    if (row < MROWS) {
      int b = row / TPC, t = row - b * TPC - 7;
      if (t >= 0 && t < 4096) src = inp + ((size_t)b * 4096 + t) * KD + c;
    } else if (row < MTOT) {
      src = pos + (size_t)(row - MROWS) * KD + c;
    }
  } else {
    int wid = gid - ACH;
    if (wid >= 512 * 96) return;
    int row = wid / 96, c = (wid - row * 96) * 8;
    dst = Wbf + (size_t)row * KD + c;
    src = (row < 256) ? Wq + (size_t)row * KD + c
                      : Wv + (size_t)(row - 256) * KD + c;
  }
  uint4 o;
  if (src) {
    float4 f0 = *(const float4*)src;
    float4 f1 = *(const float4*)(src + 4);
    o.x = pack2(f0.x, f0.y); o.y = pack2(f0.z, f0.w);
    o.z = pack2(f1.x, f1.y); o.w = pack2(f1.z, f1.w);
  } else {
    o.x = o.y = o.z = o.w = 0u;
  }
  *(uint4*)dst = o;
}

// ---------------------------------------------------------------------------
// Pass 2: C[MPAD][512] = Abf @ Wbf^T. bf16 MFMA 16x16x32, 64(m) x 128(n)
// tiles, BK=32, 520 blocks (~2/CU). Both operands staged with
// global_load_lds width-16 (zero-VALU staging; m97 pattern). bf16 outputs in
// attention-friendly layout q/v [B][H][TPC][64]; pos rows -> [15][256].
__global__ __launch_bounds__(256) void gemm_bf16(
    const ushort* __restrict__ Abf, const ushort* __restrict__ Wbf,
    const float* __restrict__ bq, const float* __restrict__ bv,
    ushort* __restrict__ q_out, ushort* __restrict__ v_out,
    ushort* __restrict__ pos_q, ushort* __restrict__ pos_v) {
  __shared__ ushort Al[64 * 32];
  __shared__ ushort Bl[128 * 32];
  const int tid = threadIdx.x;
  const int wave = tid >> 6, lane = tid & 63;
  const int ns = blockIdx.x;            // 0..3 (0-1 -> q, 2-3 -> v)
  const int m0 = blockIdx.y * 64;
  const int wm = wave & 1, wn = wave >> 1;
  const int fr = lane & 15, quad = lane >> 4;

  // staging: chunk idx -> row = idx>>2, kc = (idx&3)*8
  const int srow = tid >> 2, skc = (tid & 3) * 8;
  const ushort* ag  = Abf + (size_t)(m0 + srow) * KD + skc;
  const ushort* bg0 = Wbf + (size_t)(ns * 128 + srow) * KD + skc;
  const ushort* bg1 = bg0 + (size_t)64 * KD;
  ushort* al  = Al + wave * 512;          // + lane*8 implicit (HW adds lane*16B)
  ushort* bl0 = Bl + wave * 512;
  ushort* bl1 = Bl + 2048 + wave * 512;

  f32x4 acc[2][4];
  #pragma unroll
  for (int i = 0; i < 2; i++)
    #pragma unroll
    for (int j = 0; j < 4; j++) acc[i][j] = 0.0f;

  for (int k0 = 0; k0 < KD; k0 += 32) {
    LOAD_LDS16(ag + k0, al);
    LOAD_LDS16(bg0 + k0, bl0);
    LOAD_LDS16(bg1 + k0, bl1);
    __syncthreads();
    short8 af[2], bf[4];
    #pragma unroll
    for (int i = 0; i < 2; i++)
      af[i] = *(const short8*)(Al + (wm * 32 + i * 16 + fr) * 32 + quad * 8);
    #pragma unroll
    for (int j = 0; j < 4; j++)
      bf[j] = *(const short8*)(Bl + (wn * 64 + j * 16 + fr) * 32 + quad * 8);
    #pragma unroll
    for (int i = 0; i < 2; i++)
      #pragma unroll
      for (int j = 0; j < 4; j++)
        acc[i][j] = __builtin_amdgcn_mfma_f32_16x16x32_bf16(af[i], bf[j],
                                                            acc[i][j], 0, 0, 0);
    __syncthreads();
  }

  // epilogue: C/D layout col=lane&15 (n), row=quad*4+reg (m); bf16 stores
  const float* bias = (ns < 2) ? bq : bv;
  ushort* outp = (ns < 2) ? q_out : v_out;
  ushort* posp = (ns < 2) ? pos_q : pos_v;
  const int wbase = (ns & 1) * 128;
  #pragma unroll
  for (int j = 0; j < 4; j++) {
    const int colq = wbase + wn * 64 + j * 16 + fr;   // 0..255
    const int h = colq >> 6, d = colq & 63;
    const float bj = bias[colq];
    #pragma unroll
    for (int i = 0; i < 2; i++) {
      const int mb = m0 + wm * 32 + i * 16 + quad * 4;
      #pragma unroll
      for (int r = 0; r < 4; r++) {
        const int m = mb + r;
        if (m < MROWS) {
          int b = m / TPC, tp = m - b * TPC;
          outp[(((size_t)(b * 4 + h)) * TPC + tp) * 64 + d] =
              (ushort)bfr(acc[i][j][r] + bj);
        } else if (m < MTOT) {
          posp[(m - MROWS) * 256 + colq] = (ushort)bfr(acc[i][j][r]);
        }
      }
    }
  }
}

// ---------------------------------------------------------------------------
// Pass 3: windowed attention. bf16 k/v/pos in ([B][H][TPC][64] layout ->
// contiguous 78-row slab per block), converted to fp32 once at LDS staging.
// Block = (b, h, 64-t tile); thread = (t_local, quarter of DH); 2-step
// 4-lane shuffle for the dot. fp32 output.
__global__ __launch_bounds__(256) void win_attn4(
    const ushort* __restrict__ q_out, const ushort* __restrict__ v_out,
    const ushort* __restrict__ pos_q, const ushort* __restrict__ pos_v,
    float* __restrict__ out) {
  __shared__ __align__(16) float ks[78][68];
  __shared__ __align__(16) float vs[78][68];
  __shared__ __align__(16) float pq[15][68];
  __shared__ __align__(16) float pv[15][68];
  const int tid = threadIdx.x;
  const int bh = blockIdx.x >> 6, tile = blockIdx.x & 63;
  const int b = bh >> 2, h = bh & 3;
  const int t0 = tile * 64;

  const size_t slab = (((size_t)(b * 4 + h)) * TPC + t0) * 64;
  // 78*64 = 4992 bf16 per slab = 624 chunks of 8 (contiguous)
  for (int idx = tid; idx < 624; idx += 256) {
    int row = idx >> 3, c8 = (idx & 7) * 8;
    uint4 kc = *(const uint4*)(q_out + slab + idx * 8);
    ks[row][c8 + 0] = bflo(kc.x); ks[row][c8 + 1] = bfhi(kc.x);
    ks[row][c8 + 2] = bflo(kc.y); ks[row][c8 + 3] = bfhi(kc.y);
    ks[row][c8 + 4] = bflo(kc.z); ks[row][c8 + 5] = bfhi(kc.z);
    ks[row][c8 + 6] = bflo(kc.w); ks[row][c8 + 7] = bfhi(kc.w);
    uint4 vc = *(const uint4*)(v_out + slab + idx * 8);
    vs[row][c8 + 0] = bflo(vc.x); vs[row][c8 + 1] = bfhi(vc.x);
    vs[row][c8 + 2] = bflo(vc.y); vs[row][c8 + 3] = bfhi(vc.y);
    vs[row][c8 + 4] = bflo(vc.z); vs[row][c8 + 5] = bfhi(vc.z);
    vs[row][c8 + 6] = bflo(vc.w); vs[row][c8 + 7] = bfhi(vc.w);
  }
  if (tid < 120) {
    int row = tid >> 3, c8 = (tid & 7) * 8;
    uint4 qc = *(const uint4*)(pos_q + row * 256 + h * 64 + c8);
    pq[row][c8 + 0] = bflo(qc.x); pq[row][c8 + 1] = bfhi(qc.x);
    pq[row][c8 + 2] = bflo(qc.y); pq[row][c8 + 3] = bfhi(qc.y);
    pq[row][c8 + 4] = bflo(qc.z); pq[row][c8 + 5] = bfhi(qc.z);
    pq[row][c8 + 6] = bflo(qc.w); pq[row][c8 + 7] = bfhi(qc.w);
    uint4 vc = *(const uint4*)(pos_v + row * 256 + h * 64 + c8);
    pv[row][c8 + 0] = bflo(vc.x); pv[row][c8 + 1] = bfhi(vc.x);
    pv[row][c8 + 2] = bflo(vc.y); pv[row][c8 + 3] = bfhi(vc.y);
    pv[row][c8 + 4] = bflo(vc.z); pv[row][c8 + 5] = bfhi(vc.z);
    pv[row][c8 + 6] = bflo(vc.w); pv[row][c8 + 7] = bfhi(vc.w);
  }
  __syncthreads();

  const int tl = tid >> 2, qtr = tid & 3, d0 = qtr * 16;
  float4 qv[4];
  #pragma unroll
  for (int c = 0; c < 4; c++) qv[c] = *(float4*)&ks[tl + 7][d0 + c * 4];
  float4 ctx[4];
  #pragma unroll
  for (int c = 0; c < 4; c++) ctx[c] = make_float4(0.f, 0.f, 0.f, 0.f);

  #pragma unroll
  for (int w = 0; w < 15; w++) {
    float p = 0.f;
    #pragma unroll
    for (int c = 0; c < 4; c++) {
      float4 kk = *(float4*)&ks[tl + w][d0 + c * 4];
      float4 pp = *(float4*)&pq[w][d0 + c * 4];
      p += qv[c].x * (kk.x + pp.x) + qv[c].y * (kk.y + pp.y) +
           qv[c].z * (kk.z + pp.z) + qv[c].w * (kk.w + pp.w);
    }
    p += __shfl_xor(p, 1, 64);
    p += __shfl_xor(p, 2, 64);
    #pragma unroll
    for (int c = 0; c < 4; c++) {
      float4 vv = *(float4*)&vs[tl + w][d0 + c * 4];
      float4 pp = *(float4*)&pv[w][d0 + c * 4];
      ctx[c].x += p * (vv.x + pp.x);
      ctx[c].y += p * (vv.y + pp.y);
      ctx[c].z += p * (vv.z + pp.z);
      ctx[c].w += p * (vv.w + pp.w);
    }
  }
  size_t oo = ((size_t)(b * 4096 + t0 + tl)) * 256 + h * 64 + d0;
  #pragma unroll
  for (int c = 0; c < 4; c++) *(float4*)(out + oo + c * 4) = ctx[c];
}

// ---------------------------------------------------------------------------
extern "C" void kernel_launch(void* const* d_in, const int* in_sizes, int n_in,
                              void* d_out, int out_size, void* d_ws,
                              size_t ws_size, hipStream_t stream) {
  const float* inp = (const float*)d_in[0];
  const float* Wq  = (const float*)d_in[1];
  const float* bq  = (const float*)d_in[2];
  const float* Wv  = (const float*)d_in[3];
  const float* bv  = (const float*)d_in[4];
  const float* pos = (const float*)d_in[5];
  float* out = (float*)d_out;

  // ws layout (bytes, all bf16 except noted):
  // Abf 12,779,520 | Wbf 786,432 | q_out 4,208,640 | v_out 4,208,640 |
  // pos_q 7,680 | pos_v 7,680  -> ~22.0 MB
  char* ws = (char*)d_ws;
  ushort* Abf   = (ushort*)ws;
  ushort* Wbf   = (ushort*)(ws + 12779520);
  ushort* q_out = (ushort*)(ws + 13565952);   // [B][H][TPC][64]
  ushort* v_out = (ushort*)(ws + 17774592);
  ushort* pos_q = (ushort*)(ws + 21983232);   // [15][256]
  ushort* pos_v = (ushort*)(ws + 21990912);

  const int cast_chunks = MPAD * 96 + 512 * 96;        // 847,872
  hipLaunchKernelGGL(cast_ab, dim3(cast_chunks / 256), dim3(256), 0, stream,
                     inp, Wq, Wv, pos, Abf, Wbf);
  hipLaunchKernelGGL(gemm_bf16, dim3(4, MPAD / 64), dim3(256), 0, stream,
                     Abf, Wbf, bq, bv, q_out, v_out, pos_q, pos_v);
  hipLaunchKernelGGL(win_attn4, dim3(2 * 4 * 64), dim3(256), 0, stream,
                     q_out, v_out, pos_q, pos_v, out);
}

// Round 5
// 109.860 us; speedup vs baseline: 2.0888x; 1.0299x over previous
//
#include <hip/hip_runtime.h>

// MyAttention: B=2, T=4096, D=768, DO=256, H=4, DH=64, W2=15
#define TPC   4110            // T + 14 (padded seq)
#define MROWS 8220            // B * TPC
#define MTOT  8235            // + 15 pos rows
#define MPAD  8320            // 130 * 64
#define KD    768

typedef __attribute__((ext_vector_type(8))) short short8;
typedef __attribute__((ext_vector_type(4))) float f32x4;

#define LOAD_LDS16(gp, lp)                                                   \
  __builtin_amdgcn_global_load_lds(                                          \
      (const __attribute__((address_space(1))) void*)(gp),                   \
      (__attribute__((address_space(3))) void*)(lp), 16, 0, 0)

__device__ inline unsigned bfr(float x) {
  unsigned u = __float_as_uint(x);
  return (u + 0x7FFFu + ((u >> 16) & 1u)) >> 16;   // RNE fp32->bf16
}
__device__ inline unsigned pack2(float a, float b) {
  return bfr(a) | (bfr(b) << 16);
}
__device__ inline float bflo(unsigned u) { return __uint_as_float(u << 16); }
__device__ inline float bfhi(unsigned u) { return __uint_as_float(u & 0xffff0000u); }

// ---------------------------------------------------------------------------
// Pass 1: cast A (zero-padded inputs + 15 pos rows, MPAD x 768) and W
// ([Wq;Wv], 512 x 768) to bf16. One 16B chunk (8 bf16) per thread.
// Pure streaming, ~41 MB -> BW-bound (~7 us), at floor.
__global__ __launch_bounds__(256) void cast_ab(
    const float* __restrict__ inp, const float* __restrict__ Wq,
    const float* __restrict__ Wv, const float* __restrict__ pos,
    ushort* __restrict__ Abf, ushort* __restrict__ Wbf) {
  const int ACH = MPAD * 96;
  int gid = blockIdx.x * 256 + threadIdx.x;
  const float* src = nullptr;
  ushort* dst;
  if (gid < ACH) {
    int row = gid / 96, c = (gid - row * 96) * 8;
    dst = Abf + (size_t)row * KD + c;
    if (row < MROWS) {
      int b = row / TPC, t = row - b * TPC - 7;
      if (t >= 0 && t < 4096) src = inp + ((size_t)b * 4096 + t) * KD + c;
    } else if (row < MTOT) {
      src = pos + (size_t)(row - MROWS) * KD + c;
    }
  } else {
    int wid = gid - ACH;
    if (wid >= 512 * 96) return;
    int row = wid / 96, c = (wid - row * 96) * 8;
    dst = Wbf + (size_t)row * KD + c;
    src = (row < 256) ? Wq + (size_t)row * KD + c
                      : Wv + (size_t)(row - 256) * KD + c;
  }
  uint4 o;
  if (src) {
    float4 f0 = *(const float4*)src;
    float4 f1 = *(const float4*)(src + 4);
    o.x = pack2(f0.x, f0.y); o.y = pack2(f0.z, f0.w);
    o.z = pack2(f1.x, f1.y); o.w = pack2(f1.z, f1.w);
  } else {
    o.x = o.y = o.z = o.w = 0u;
  }
  *(uint4*)dst = o;
}

// ---------------------------------------------------------------------------
// Pass 2: C[MPAD][512] = Abf @ Wbf^T. bf16 MFMA 16x16x32, 64(m) x 128(n)
// tiles, BK=64 (12 barrier-iters instead of 24 -- halves the syncthreads
// vmcnt-drain stalls), 520 blocks (~2/CU), global_load_lds width-16 staging.
// k-chunks XOR-swizzled by (row&7) inside each 128B row so fragment
// ds_read_b128 stays at the 8-cycle wave64 minimum (row stride 128B would
// otherwise alias all rows onto one bank group = 16-way conflict).
// bf16 outputs in attention layout q/v [B][H][TPC][64]; pos -> [15][256].
__global__ __launch_bounds__(256) void gemm_bf16(
    const ushort* __restrict__ Abf, const ushort* __restrict__ Wbf,
    const float* __restrict__ bq, const float* __restrict__ bv,
    ushort* __restrict__ q_out, ushort* __restrict__ v_out,
    ushort* __restrict__ pos_q, ushort* __restrict__ pos_v) {
  __shared__ ushort Al[64 * 64];    // 8 KB
  __shared__ ushort Bl[128 * 64];   // 16 KB
  const int tid = threadIdx.x;
  const int wave = tid >> 6, lane = tid & 63;
  const int ns = blockIdx.x;            // 0..3 (0-1 -> q, 2-3 -> v)
  const int m0 = blockIdx.y * 64;
  const int wm = wave & 1, wn = wave >> 1;
  const int fr = lane & 15, quad = lane >> 4;

  // staging: chunk c -> row = c>>3, logical k-chunk kq = c&7,
  // swizzled global source chunk = kq ^ (row&7).
  // A: 512 chunks (2 issues), B: 1024 chunks (4 issues).
  const ushort* ag[2];
  #pragma unroll
  for (int i = 0; i < 2; i++) {
    int c = i * 256 + tid, row = c >> 3, kq = c & 7;
    ag[i] = Abf + (size_t)(m0 + row) * KD + ((kq ^ (row & 7)) * 8);
  }
  const ushort* bg[4];
  #pragma unroll
  for (int i = 0; i < 4; i++) {
    int c = i * 256 + tid, row = c >> 3, kq = c & 7;
    bg[i] = Wbf + (size_t)(ns * 128 + row) * KD + ((kq ^ (row & 7)) * 8);
  }
  ushort* al[2];
  ushort* bl[4];
  #pragma unroll
  for (int i = 0; i < 2; i++) al[i] = Al + (i * 256 + wave * 64) * 8;
  #pragma unroll
  for (int i = 0; i < 4; i++) bl[i] = Bl + (i * 256 + wave * 64) * 8;

  f32x4 acc[2][4];
  #pragma unroll
  for (int i = 0; i < 2; i++)
    #pragma unroll
    for (int j = 0; j < 4; j++) acc[i][j] = 0.0f;

  for (int k0 = 0; k0 < KD; k0 += 64) {
    #pragma unroll
    for (int i = 0; i < 2; i++) LOAD_LDS16(ag[i] + k0, al[i]);
    #pragma unroll
    for (int i = 0; i < 4; i++) LOAD_LDS16(bg[i] + k0, bl[i]);
    __syncthreads();
    short8 af[2][2], bf[2][4];
    #pragma unroll
    for (int ks = 0; ks < 2; ks++) {
      const int e = ((ks * 4 + quad) ^ (fr & 7)) * 8;   // un-swizzle
      #pragma unroll
      for (int i = 0; i < 2; i++)
        af[ks][i] = *(const short8*)(Al + (wm * 32 + i * 16 + fr) * 64 + e);
      #pragma unroll
      for (int j = 0; j < 4; j++)
        bf[ks][j] = *(const short8*)(Bl + (wn * 64 + j * 16 + fr) * 64 + e);
    }
    #pragma unroll
    for (int ks = 0; ks < 2; ks++)
      #pragma unroll
      for (int i = 0; i < 2; i++)
        #pragma unroll
        for (int j = 0; j < 4; j++)
          acc[i][j] = __builtin_amdgcn_mfma_f32_16x16x32_bf16(
              af[ks][i], bf[ks][j], acc[i][j], 0, 0, 0);
    __syncthreads();
  }

  // epilogue: C/D layout col=lane&15 (n), row=quad*4+reg (m); bf16 stores
  const float* bias = (ns < 2) ? bq : bv;
  ushort* outp = (ns < 2) ? q_out : v_out;
  ushort* posp = (ns < 2) ? pos_q : pos_v;
  const int wbase = (ns & 1) * 128;
  #pragma unroll
  for (int j = 0; j < 4; j++) {
    const int colq = wbase + wn * 64 + j * 16 + fr;   // 0..255
    const int h = colq >> 6, d = colq & 63;
    const float bj = bias[colq];
    #pragma unroll
    for (int i = 0; i < 2; i++) {
      const int mb = m0 + wm * 32 + i * 16 + quad * 4;
      #pragma unroll
      for (int r = 0; r < 4; r++) {
        const int m = mb + r;
        if (m < MROWS) {
          int b = m / TPC, tp = m - b * TPC;
          outp[(((size_t)(b * 4 + h)) * TPC + tp) * 64 + d] =
              (ushort)bfr(acc[i][j][r] + bj);
        } else if (m < MTOT) {
          posp[(m - MROWS) * 256 + colq] = (ushort)bfr(acc[i][j][r]);
        }
      }
    }
  }
}

// ---------------------------------------------------------------------------
// Pass 3: windowed attention. bf16 k/v/pos in ([B][H][TPC][64] layout ->
// contiguous 78-row slab per block), converted to fp32 once at LDS staging.
// Block = (b, h, 64-t tile); thread = (t_local, quarter of DH); 2-step
// 4-lane shuffle for the dot. fp32 output. ~16.5 MB traffic, near BW floor.
__global__ __launch_bounds__(256) void win_attn4(
    const ushort* __restrict__ q_out, const ushort* __restrict__ v_out,
    const ushort* __restrict__ pos_q, const ushort* __restrict__ pos_v,
    float* __restrict__ out) {
  __shared__ __align__(16) float ks[78][68];
  __shared__ __align__(16) float vs[78][68];
  __shared__ __align__(16) float pq[15][68];
  __shared__ __align__(16) float pv[15][68];
  const int tid = threadIdx.x;
  const int bh = blockIdx.x >> 6, tile = blockIdx.x & 63;
  const int b = bh >> 2, h = bh & 3;
  const int t0 = tile * 64;

  const size_t slab = (((size_t)(b * 4 + h)) * TPC + t0) * 64;
  for (int idx = tid; idx < 624; idx += 256) {
    int row = idx >> 3, c8 = (idx & 7) * 8;
    uint4 kc = *(const uint4*)(q_out + slab + idx * 8);
    ks[row][c8 + 0] = bflo(kc.x); ks[row][c8 + 1] = bfhi(kc.x);
    ks[row][c8 + 2] = bflo(kc.y); ks[row][c8 + 3] = bfhi(kc.y);
    ks[row][c8 + 4] = bflo(kc.z); ks[row][c8 + 5] = bfhi(kc.z);
    ks[row][c8 + 6] = bflo(kc.w); ks[row][c8 + 7] = bfhi(kc.w);
    uint4 vc = *(const uint4*)(v_out + slab + idx * 8);
    vs[row][c8 + 0] = bflo(vc.x); vs[row][c8 + 1] = bfhi(vc.x);
    vs[row][c8 + 2] = bflo(vc.y); vs[row][c8 + 3] = bfhi(vc.y);
    vs[row][c8 + 4] = bflo(vc.z); vs[row][c8 + 5] = bfhi(vc.z);
    vs[row][c8 + 6] = bflo(vc.w); vs[row][c8 + 7] = bfhi(vc.w);
  }
  if (tid < 120) {
    int row = tid >> 3, c8 = (tid & 7) * 8;
    uint4 qc = *(const uint4*)(pos_q + row * 256 + h * 64 + c8);
    pq[row][c8 + 0] = bflo(qc.x); pq[row][c8 + 1] = bfhi(qc.x);
    pq[row][c8 + 2] = bflo(qc.y); pq[row][c8 + 3] = bfhi(qc.y);
    pq[row][c8 + 4] = bflo(qc.z); pq[row][c8 + 5] = bfhi(qc.z);
    pq[row][c8 + 6] = bflo(qc.w); pq[row][c8 + 7] = bfhi(qc.w);
    uint4 vc = *(const uint4*)(pos_v + row * 256 + h * 64 + c8);
    pv[row][c8 + 0] = bflo(vc.x); pv[row][c8 + 1] = bfhi(vc.x);
    pv[row][c8 + 2] = bflo(vc.y); pv[row][c8 + 3] = bfhi(vc.y);
    pv[row][c8 + 4] = bflo(vc.z); pv[row][c8 + 5] = bfhi(vc.z);
    pv[row][c8 + 6] = bflo(vc.w); pv[row][c8 + 7] = bfhi(vc.w);
  }
  __syncthreads();

  const int tl = tid >> 2, qtr = tid & 3, d0 = qtr * 16;
  float4 qv[4];
  #pragma unroll
  for (int c = 0; c < 4; c++) qv[c] = *(float4*)&ks[tl + 7][d0 + c * 4];
  float4 ctx[4];
  #pragma unroll
  for (int c = 0; c < 4; c++) ctx[c] = make_float4(0.f, 0.f, 0.f, 0.f);

  #pragma unroll
  for (int w = 0; w < 15; w++) {
    float p = 0.f;
    #pragma unroll
    for (int c = 0; c < 4; c++) {
      float4 kk = *(float4*)&ks[tl + w][d0 + c * 4];
      float4 pp = *(float4*)&pq[w][d0 + c * 4];
      p += qv[c].x * (kk.x + pp.x) + qv[c].y * (kk.y + pp.y) +
           qv[c].z * (kk.z + pp.z) + qv[c].w * (kk.w + pp.w);
    }
    p += __shfl_xor(p, 1, 64);
    p += __shfl_xor(p, 2, 64);
    #pragma unroll
    for (int c = 0; c < 4; c++) {
      float4 vv = *(float4*)&vs[tl + w][d0 + c * 4];
      float4 pp = *(float4*)&pv[w][d0 + c * 4];
      ctx[c].x += p * (vv.x + pp.x);
      ctx[c].y += p * (vv.y + pp.y);
      ctx[c].z += p * (vv.z + pp.z);
      ctx[c].w += p * (vv.w + pp.w);
    }
  }
  size_t oo = ((size_t)(b * 4096 + t0 + tl)) * 256 + h * 64 + d0;
  #pragma unroll
  for (int c = 0; c < 4; c++) *(float4*)(out + oo + c * 4) = ctx[c];
}

// ---------------------------------------------------------------------------
extern "C" void kernel_launch(void* const* d_in, const int* in_sizes, int n_in,
                              void* d_out, int out_size, void* d_ws,
                              size_t ws_size, hipStream_t stream) {
  const float* inp = (const float*)d_in[0];
  const float* Wq  = (const float*)d_in[1];
  const float* bq  = (const float*)d_in[2];
  const float* Wv  = (const float*)d_in[3];
  const float* bv  = (const float*)d_in[4];
  const float* pos = (const float*)d_in[5];
  float* out = (float*)d_out;

  // ws layout (bytes): Abf 12,779,520 | Wbf 786,432 | q_out 4,208,640 |
  // v_out 4,208,640 | pos_q 7,680 | pos_v 7,680  -> ~22.0 MB
  char* ws = (char*)d_ws;
  ushort* Abf   = (ushort*)ws;
  ushort* Wbf   = (ushort*)(ws + 12779520);
  ushort* q_out = (ushort*)(ws + 13565952);   // [B][H][TPC][64] bf16
  ushort* v_out = (ushort*)(ws + 17774592);
  ushort* pos_q = (ushort*)(ws + 21983232);   // [15][256] bf16
  ushort* pos_v = (ushort*)(ws + 21990912);

  const int cast_chunks = MPAD * 96 + 512 * 96;        // 847,872
  hipLaunchKernelGGL(cast_ab, dim3(cast_chunks / 256), dim3(256), 0, stream,
                     inp, Wq, Wv, pos, Abf, Wbf);
  hipLaunchKernelGGL(gemm_bf16, dim3(4, MPAD / 64), dim3(256), 0, stream,
                     Abf, Wbf, bq, bv, q_out, v_out, pos_q, pos_v);
  hipLaunchKernelGGL(win_attn4, dim3(2 * 4 * 64), dim3(256), 0, stream,
                     q_out, v_out, pos_q, pos_v, out);
}